// Round 2
// baseline (561.778 us; speedup 1.0000x reference)
//
#include <hip/hip_runtime.h>
#include <cstdint>
#include <cstddef>

#define N_NODES 50000
#define N_EDGES 400000
#define E_TOT   (N_EDGES + N_NODES)   // with self-loops
#define D_INF   128
#define C1      256                   // 8 heads * 32
#define HIDC    32
#define OUTC    16
#define NEG_SLOPE 0.2f

typedef __bf16 bf16x8 __attribute__((ext_vector_type(8)));
typedef float  floatx4 __attribute__((ext_vector_type(4)));
typedef unsigned int uintx4 __attribute__((ext_vector_type(4)));
typedef unsigned short ushortx8 __attribute__((ext_vector_type(8)));

__device__ __forceinline__ unsigned short f2bf(float f) {
  unsigned int u = __builtin_bit_cast(unsigned int, f);
  u += 0x7FFFu + ((u >> 16) & 1u);   // RNE (finite values)
  return (unsigned short)(u >> 16);
}
__device__ __forceinline__ float bf2f(unsigned short u) {
  return __builtin_bit_cast(float, (unsigned int)u << 16);
}

// ---------- edge_index word-width autodetect ----------
// int64 input: odd int32 words are high halves of values < 2^31 -> all zero.
__global__ void k_detect(const int* __restrict__ ei, int* __restrict__ flag) {
  __shared__ int s;
  if (threadIdx.x == 0) s = 0;
  __syncthreads();
  atomicOr(&s, ei[2 * threadIdx.x + 1]);
  __syncthreads();
  if (threadIdx.x == 0) *flag = (s == 0) ? 1 : 0;   // 1 = int64
}

__device__ __forceinline__ int ld_src(const int* ei, int f, int e) {
  return f ? ei[2 * e] : ei[e];
}
__device__ __forceinline__ int ld_dst(const int* ei, int f, int e) {
  return f ? ei[2 * (N_EDGES + e)] : ei[N_EDGES + e];
}

// ---------- transpose + f32->bf16: in[R][C] f32 -> out[C][R] bf16 ----------
__global__ void k_transpose(const float* __restrict__ in,
                            unsigned short* __restrict__ out, int R, int C) {
  int i = blockIdx.x * 256 + threadIdx.x;
  if (i < R * C) {
    int r = i / C, c = i % C;
    out[c * R + r] = f2bf(in[i]);
  }
}

// ---------- CSR build ----------
__global__ void k_deg(const int* __restrict__ ei, const int* __restrict__ flag,
                      int* __restrict__ deg) {
  int e = blockIdx.x * 256 + threadIdx.x;
  if (e < E_TOT) {
    int dst = (e < N_EDGES) ? ld_dst(ei, *flag, e) : (e - N_EDGES);
    if ((unsigned)dst < N_NODES) atomicAdd(&deg[dst], 1);
  }
}

// single-block exclusive scan; deg and cursor alias (in-place ok)
__global__ __launch_bounds__(1024) void k_scan(const int* deg, int* rowptr,
                                               int* cursor, int n) {
  __shared__ int sbuf[1024];
  __shared__ int scarry;
  const int t = threadIdx.x;
  if (t == 0) scarry = 0;
  __syncthreads();
  for (int base = 0; base < n; base += 1024) {
    const int i = base + t;
    int v = (i < n) ? deg[i] : 0;
    sbuf[t] = v;
    __syncthreads();
    for (int off = 1; off < 1024; off <<= 1) {
      int add = (t >= off) ? sbuf[t - off] : 0;
      __syncthreads();
      sbuf[t] += add;
      __syncthreads();
    }
    const int incl = sbuf[t];
    const int carry = scarry;
    if (i < n) { rowptr[i] = carry + incl - v; cursor[i] = carry + incl - v; }
    __syncthreads();
    if (t == 1023) scarry = carry + incl;
    __syncthreads();
  }
  if (t == 0) rowptr[n] = scarry;
}

__global__ void k_fill(const int* __restrict__ ei, const int* __restrict__ flag,
                       int* __restrict__ cursor, int* __restrict__ esrc) {
  int e = blockIdx.x * 256 + threadIdx.x;
  if (e < E_TOT) {
    int src, dst;
    if (e < N_EDGES) { src = ld_src(ei, *flag, e); dst = ld_dst(ei, *flag, e); }
    else             { src = dst = e - N_EDGES; }
    if ((unsigned)src < N_NODES && (unsigned)dst < N_NODES) {
      int pos = atomicAdd(&cursor[dst], 1);
      esrc[pos] = src;
    }
  }
}

// ---------- A-fragment loaders (8 contiguous k-elements -> bf16x8) ----------
__device__ __forceinline__ bf16x8 load8(const unsigned short* p) {
  uintx4 raw = *reinterpret_cast<const uintx4*>(p);
  return __builtin_bit_cast(bf16x8, raw);
}
__device__ __forceinline__ bf16x8 load8(const float* p) {
  floatx4 a = *reinterpret_cast<const floatx4*>(p);
  floatx4 b = *reinterpret_cast<const floatx4*>(p + 4);
  ushortx8 u;
#pragma unroll
  for (int i = 0; i < 4; ++i) { u[i] = f2bf(a[i]); u[4 + i] = f2bf(b[i]); }
  return __builtin_bit_cast(bf16x8, u);
}

// ---------- MFMA bf16 GEMM: C[M][NCOLS] = A[M][K] * BT[NCOLS][K]^T ----------
// A may be f32 (converted on load) or bf16. BT, C are bf16.
template <int K, int NCOLS, typename AT>
__global__ __launch_bounds__(256) void k_mfma_gemm(
    const AT* __restrict__ A,
    const unsigned short* __restrict__ BT,
    unsigned short* __restrict__ C, int M) {
  const int wave = threadIdx.x >> 6;
  const int lane = threadIdx.x & 63;
  const int lo = lane & 15;   // m for A, n for B, col for C/D
  const int q  = lane >> 4;   // k-chunk quad
  const int unit = blockIdx.x * 4 + wave;
  const int r0 = unit * 32;
  if (r0 >= M) return;
  const bool two = (r0 + 16) < M;

  const AT* aptr0 = A + (size_t)(r0 + lo) * K + q * 8;
  const AT* aptr1 = A + (size_t)(r0 + 16 + lo) * K + q * 8;

#pragma unroll
  for (int nt = 0; nt < NCOLS / 16; ++nt) {
    floatx4 acc0 = {0.f, 0.f, 0.f, 0.f};
    floatx4 acc1 = {0.f, 0.f, 0.f, 0.f};
    const unsigned short* bptr = BT + (size_t)(nt * 16 + lo) * K + q * 8;
#pragma unroll
    for (int kb = 0; kb < K / 32; ++kb) {
      bf16x8 b  = load8(bptr + kb * 32);
      bf16x8 a0 = load8(aptr0 + kb * 32);
      acc0 = __builtin_amdgcn_mfma_f32_16x16x32_bf16(a0, b, acc0, 0, 0, 0);
      if (two) {
        bf16x8 a1 = load8(aptr1 + kb * 32);
        acc1 = __builtin_amdgcn_mfma_f32_16x16x32_bf16(a1, b, acc1, 0, 0, 0);
      }
    }
    // C/D layout: col = lane&15, row = (lane>>4)*4 + reg   [m89-verified]
#pragma unroll
    for (int r = 0; r < 4; ++r) {
      C[(size_t)(r0 + q * 4 + r) * NCOLS + nt * 16 + lo] = f2bf(acc0[r]);
      if (two)
        C[(size_t)(r0 + 16 + q * 4 + r) * NCOLS + nt * 16 + lo] = f2bf(acc1[r]);
    }
  }
}

// ---------- GAT layer 1: fused gather + online softmax + aggregate + bias + ELU ----------
// block = 256 threads = one dst node; thread t = channel t (head = t>>5)
// h1 may alias xr1: each block reads only its OWN xr row (at start) and
// writes only its own h1 row (at end).
__global__ __launch_bounds__(256) void k_gat1(
    const unsigned short* __restrict__ xl1, const unsigned short* __restrict__ xr1,
    const float* __restrict__ att1, const float* __restrict__ b1,
    const int* __restrict__ rowptr, const int* __restrict__ esrc,
    unsigned short* __restrict__ h1) {
  const int dst = blockIdx.x;
  const int t = threadIdx.x;
  const float xr_c  = bf2f(xr1[(size_t)dst * C1 + t]);
  const float att_c = att1[t];
  const int beg = rowptr[dst], end = rowptr[dst + 1];
  float m = -INFINITY, l = 0.f, acc = 0.f;
  for (int i = beg; i < end; ++i) {
    const int s = esrc[i];
    if ((unsigned)s >= N_NODES) continue;
    const float xl_c = bf2f(xl1[(size_t)s * C1 + t]);
    float e = xl_c + xr_c;
    e = e > 0.f ? e : NEG_SLOPE * e;
    float v = e * att_c;
    // per-head (32-lane half-wave) sum
    v += __shfl_xor(v, 1);
    v += __shfl_xor(v, 2);
    v += __shfl_xor(v, 4);
    v += __shfl_xor(v, 8);
    v += __shfl_xor(v, 16);
    if (v > m) {
      const float sc = __expf(m - v);  // first edge: exp(-inf)=0
      acc *= sc; l *= sc; m = v;
    }
    const float p = __expf(v - m);
    l += p; acc += p * xl_c;
  }
  float o = acc / fmaxf(l, 1e-16f) + b1[t];
  o = o > 0.f ? o : (__expf(o) - 1.f);  // ELU
  h1[(size_t)dst * C1 + t] = f2bf(o);
}

// ---------- GAT layer 2 (1 head, 32 ch) fused with final linear [32x16] ----------
// block = 64 (one wave) per dst; lanes 0..31 = channels; out fp32
__global__ __launch_bounds__(64) void k_gat2(
    const unsigned short* __restrict__ xl2, const unsigned short* __restrict__ xr2,
    const float* __restrict__ att2, const float* __restrict__ b2,
    const float* __restrict__ Wlin, const float* __restrict__ blin,
    const int* __restrict__ rowptr, const int* __restrict__ esrc,
    float* __restrict__ out) {
  const int dst = blockIdx.x;
  const int lane = threadIdx.x;
  __shared__ float sh[32];
  if (lane < 32) {
    const float xr_c  = bf2f(xr2[(size_t)dst * HIDC + lane]);
    const float att_c = att2[lane];
    const int beg = rowptr[dst], end = rowptr[dst + 1];
    float m = -INFINITY, l = 0.f, acc = 0.f;
    for (int i = beg; i < end; ++i) {
      const int s = esrc[i];
      if ((unsigned)s >= N_NODES) continue;
      const float xl_c = bf2f(xl2[(size_t)s * HIDC + lane]);
      float e = xl_c + xr_c;
      e = e > 0.f ? e : NEG_SLOPE * e;
      float v = e * att_c;
      v += __shfl_xor(v, 1);
      v += __shfl_xor(v, 2);
      v += __shfl_xor(v, 4);
      v += __shfl_xor(v, 8);
      v += __shfl_xor(v, 16);
      if (v > m) {
        const float sc = __expf(m - v);
        acc *= sc; l *= sc; m = v;
      }
      const float p = __expf(v - m);
      l += p; acc += p * xl_c;
    }
    float o = acc / fmaxf(l, 1e-16f) + b2[lane];
    o = o > 0.f ? o : (__expf(o) - 1.f);  // ELU
    sh[lane] = o;
  }
  __syncthreads();
  if (lane < 16) {
    float o = blin[lane];
#pragma unroll
    for (int k = 0; k < 32; ++k)
      o += sh[k] * Wlin[k * OUTC + lane];
    out[(size_t)dst * OUTC + lane] = o;
  }
}

static inline int cdiv(int a, int b) { return (a + b - 1) / b; }

extern "C" void kernel_launch(void* const* d_in, const int* in_sizes, int n_in,
                              void* d_out, int out_size, void* d_ws, size_t ws_size,
                              hipStream_t stream) {
  const float* x    = (const float*)d_in[0];
  const int*   ei   = (const int*)d_in[1];
  const float* W1l  = (const float*)d_in[2];
  const float* W1r  = (const float*)d_in[3];
  const float* att1 = (const float*)d_in[4];
  const float* b1   = (const float*)d_in[5];
  const float* W2l  = (const float*)d_in[6];
  const float* W2r  = (const float*)d_in[7];
  const float* att2 = (const float*)d_in[8];
  const float* b2   = (const float*)d_in[9];
  const float* Wlin = (const float*)d_in[10];
  const float* blin = (const float*)d_in[11];
  float* out = (float*)d_out;

  char* w = (char*)d_ws;
  auto alloc = [&](size_t bytes) -> char* {
    char* p = w;
    w += (bytes + 255) & ~(size_t)255;
    return p;
  };
  // region A: xl1 (bf16), later reused for xl2+xr2
  char* regionA = alloc((size_t)N_NODES * C1 * 2);          // 25.6 MB
  unsigned short* xl1 = (unsigned short*)regionA;
  unsigned short* xl2 = (unsigned short*)regionA;                           // 3.2 MB
  unsigned short* xr2 = (unsigned short*)(regionA + (size_t)N_NODES * HIDC * 2 + 256);
  // region B: xr1 aliased with h1 (safe: per-block own-row read-then-write)
  unsigned short* xr1 = (unsigned short*)alloc((size_t)N_NODES * C1 * 2);   // 25.6 MB
  unsigned short* h1  = xr1;
  unsigned short* W1lT = (unsigned short*)alloc((size_t)D_INF * C1 * 2);
  unsigned short* W1rT = (unsigned short*)alloc((size_t)D_INF * C1 * 2);
  unsigned short* W2lT = (unsigned short*)alloc((size_t)C1 * HIDC * 2);
  unsigned short* W2rT = (unsigned short*)alloc((size_t)C1 * HIDC * 2);
  int* rowptr = (int*)alloc((size_t)(N_NODES + 1) * 4);
  int* cursor = (int*)alloc((size_t)N_NODES * 4);
  int* esrc   = (int*)alloc((size_t)E_TOT * 4);
  int* flag   = (int*)alloc(4);

  hipMemsetAsync(cursor, 0, (size_t)N_NODES * 4, stream);
  k_detect<<<1, 64, 0, stream>>>(ei, flag);

  k_transpose<<<cdiv(D_INF * C1, 256), 256, 0, stream>>>(W1l, W1lT, D_INF, C1);
  k_transpose<<<cdiv(D_INF * C1, 256), 256, 0, stream>>>(W1r, W1rT, D_INF, C1);
  k_transpose<<<cdiv(C1 * HIDC, 256), 256, 0, stream>>>(W2l, W2lT, C1, HIDC);
  k_transpose<<<cdiv(C1 * HIDC, 256), 256, 0, stream>>>(W2r, W2rT, C1, HIDC);

  k_deg<<<cdiv(E_TOT, 256), 256, 0, stream>>>(ei, flag, cursor);
  k_scan<<<1, 1024, 0, stream>>>(cursor, rowptr, cursor, N_NODES);
  k_fill<<<cdiv(E_TOT, 256), 256, 0, stream>>>(ei, flag, cursor, esrc);

  // GEMM1: [50000,128] x [128,256] -> xl1, xr1 (bf16; A = fp32 x, converted on load)
  const int tiles16 = cdiv(N_NODES, 16);          // 3125
  const int units   = cdiv(tiles16, 2);           // 1563
  const int gblocks = cdiv(units, 4);             // 391
  k_mfma_gemm<D_INF, C1><<<gblocks, 256, 0, stream>>>(x, W1lT, xl1, N_NODES);
  k_mfma_gemm<D_INF, C1><<<gblocks, 256, 0, stream>>>(x, W1rT, xr1, N_NODES);

  k_gat1<<<N_NODES, 256, 0, stream>>>(xl1, xr1, att1, b1, rowptr, esrc, h1);

  // GEMM2: [50000,256] x [256,32] -> xl2, xr2 (A = bf16 h1)
  k_mfma_gemm<C1, HIDC><<<gblocks, 256, 0, stream>>>(h1, W2lT, xl2, N_NODES);
  k_mfma_gemm<C1, HIDC><<<gblocks, 256, 0, stream>>>(h1, W2rT, xr2, N_NODES);

  k_gat2<<<N_NODES, 64, 0, stream>>>(xl2, xr2, att2, b2, Wlin, blin, rowptr, esrc, out);
}

// Round 3
// 389.792 us; speedup vs baseline: 1.4412x; 1.4412x over previous
//
#include <hip/hip_runtime.h>
#include <cstdint>
#include <cstddef>

#define N_NODES 50000
#define N_EDGES 400000
#define E_TOT   (N_EDGES + N_NODES)   // with self-loops
#define D_INF   128
#define C1      256                   // 8 heads * 32
#define HIDC    32
#define OUTC    16
#define NEG_SLOPE 0.2f

typedef __bf16 bf16x8 __attribute__((ext_vector_type(8)));
typedef float  floatx4 __attribute__((ext_vector_type(4)));
typedef unsigned int uintx4 __attribute__((ext_vector_type(4)));
typedef unsigned short ushortx8 __attribute__((ext_vector_type(8)));
typedef unsigned short ushortx4 __attribute__((ext_vector_type(4)));

__device__ __forceinline__ unsigned short f2bf(float f) {
  unsigned int u = __builtin_bit_cast(unsigned int, f);
  u += 0x7FFFu + ((u >> 16) & 1u);   // RNE (finite values)
  return (unsigned short)(u >> 16);
}
__device__ __forceinline__ float bf2f(unsigned short u) {
  return __builtin_bit_cast(float, (unsigned int)u << 16);
}

// ---------- edge_index word-width autodetect ----------
__global__ void k_detect(const int* __restrict__ ei, int* __restrict__ flag) {
  __shared__ int s;
  if (threadIdx.x == 0) s = 0;
  __syncthreads();
  atomicOr(&s, ei[2 * threadIdx.x + 1]);
  __syncthreads();
  if (threadIdx.x == 0) *flag = (s == 0) ? 1 : 0;   // 1 = int64
}
__device__ __forceinline__ int ld_src(const int* ei, int f, int e) {
  return f ? ei[2 * e] : ei[e];
}
__device__ __forceinline__ int ld_dst(const int* ei, int f, int e) {
  return f ? ei[2 * (N_EDGES + e)] : ei[N_EDGES + e];
}

// ---------- transpose + f32->bf16: in[R][C] f32 -> out[C][R] bf16 ----------
__global__ void k_transpose(const float* __restrict__ in,
                            unsigned short* __restrict__ out, int R, int C) {
  int i = blockIdx.x * 256 + threadIdx.x;
  if (i < R * C) {
    int r = i / C, c = i % C;
    out[c * R + r] = f2bf(in[i]);
  }
}

// ---------- CSR build ----------
__global__ void k_deg(const int* __restrict__ ei, const int* __restrict__ flag,
                      int* __restrict__ deg) {
  int e = blockIdx.x * 256 + threadIdx.x;
  if (e < E_TOT) {
    int dst = (e < N_EDGES) ? ld_dst(ei, *flag, e) : (e - N_EDGES);
    if ((unsigned)dst < N_NODES) atomicAdd(&deg[dst], 1);
  }
}

// chunked single-block exclusive scan; deg and cursor may alias (in-place ok)
__global__ __launch_bounds__(1024) void k_scan(const int* deg, int* rowptr,
                                               int* cursor, int n) {
  __shared__ int sums[1024];
  const int t = threadIdx.x;
  const int CH = (n + 1023) / 1024;
  const int base = t * CH;
  int s = 0;
  for (int j = 0; j < CH; ++j) {
    int i = base + j;
    if (i < n) s += deg[i];
  }
  sums[t] = s;
  __syncthreads();
  for (int off = 1; off < 1024; off <<= 1) {
    int add = (t >= off) ? sums[t - off] : 0;
    __syncthreads();
    sums[t] += add;
    __syncthreads();
  }
  int run = sums[t] - s;   // exclusive prefix of this chunk
  for (int j = 0; j < CH; ++j) {
    int i = base + j;
    if (i < n) {
      int d = deg[i];
      rowptr[i] = run;
      cursor[i] = run;
      run += d;
    }
  }
  __syncthreads();
  if (t == 0) rowptr[n] = sums[1023];
}

__global__ void k_fill(const int* __restrict__ ei, const int* __restrict__ flag,
                       int* __restrict__ cursor, int* __restrict__ esrc) {
  int e = blockIdx.x * 256 + threadIdx.x;
  if (e < E_TOT) {
    int src, dst;
    if (e < N_EDGES) { src = ld_src(ei, *flag, e); dst = ld_dst(ei, *flag, e); }
    else             { src = dst = e - N_EDGES; }
    if ((unsigned)src < N_NODES && (unsigned)dst < N_NODES) {
      int pos = atomicAdd(&cursor[dst], 1);
      esrc[pos] = src;
    }
  }
}

// ---------- A-fragment loaders (8 contiguous k-elements -> bf16x8) ----------
__device__ __forceinline__ bf16x8 load8(const unsigned short* p) {
  uintx4 raw = *reinterpret_cast<const uintx4*>(p);
  return __builtin_bit_cast(bf16x8, raw);
}
__device__ __forceinline__ bf16x8 load8(const float* p) {
  floatx4 a = *reinterpret_cast<const floatx4*>(p);
  floatx4 b = *reinterpret_cast<const floatx4*>(p + 4);
  ushortx8 u;
#pragma unroll
  for (int i = 0; i < 4; ++i) { u[i] = f2bf(a[i]); u[4 + i] = f2bf(b[i]); }
  return __builtin_bit_cast(bf16x8, u);
}

// ---------- dual MFMA bf16 GEMM: C{0,1}[M][NCOLS] = A[M][K] * BT{0,1}^T ----------
// A fragments loaded ONCE into registers, reused for both B matrices and all
// column tiles.  A may be f32 (converted on load) or bf16.
template <int K, int NCOLS, typename AT>
__global__ __launch_bounds__(256) void k_gemm_dual(
    const AT* __restrict__ A,
    const unsigned short* __restrict__ BT0, const unsigned short* __restrict__ BT1,
    unsigned short* __restrict__ C0, unsigned short* __restrict__ C1_, int M) {
  const int wave = threadIdx.x >> 6;
  const int lane = threadIdx.x & 63;
  const int lo = lane & 15;   // m for A, n for B, col for C/D
  const int q  = lane >> 4;   // k-chunk quad
  const int unit = blockIdx.x * 4 + wave;
  const int r0 = unit * 32;
  if (r0 >= M) return;
  const bool two = (r0 + 16) < M;
  constexpr int KB = K / 32;

  bf16x8 afrag[2][KB];
#pragma unroll
  for (int kb = 0; kb < KB; ++kb)
    afrag[0][kb] = load8(A + (size_t)(r0 + lo) * K + kb * 32 + q * 8);
  if (two) {
#pragma unroll
    for (int kb = 0; kb < KB; ++kb)
      afrag[1][kb] = load8(A + (size_t)(r0 + 16 + lo) * K + kb * 32 + q * 8);
  }

#pragma unroll
  for (int o = 0; o < 2; ++o) {
    const unsigned short* BT = o ? BT1 : BT0;
    unsigned short* C = o ? C1_ : C0;
#pragma unroll
    for (int nt = 0; nt < NCOLS / 16; ++nt) {
      floatx4 acc0 = {0.f, 0.f, 0.f, 0.f};
      floatx4 acc1 = {0.f, 0.f, 0.f, 0.f};
      const unsigned short* bptr = BT + (size_t)(nt * 16 + lo) * K + q * 8;
#pragma unroll
      for (int kb = 0; kb < KB; ++kb) {
        bf16x8 b = load8(bptr + kb * 32);
        acc0 = __builtin_amdgcn_mfma_f32_16x16x32_bf16(afrag[0][kb], b, acc0, 0, 0, 0);
        if (two)
          acc1 = __builtin_amdgcn_mfma_f32_16x16x32_bf16(afrag[1][kb], b, acc1, 0, 0, 0);
      }
      // C/D layout: col = lane&15, row = (lane>>4)*4 + reg   [m89-verified]
#pragma unroll
      for (int r = 0; r < 4; ++r) {
        C[(size_t)(r0 + q * 4 + r) * NCOLS + nt * 16 + lo] = f2bf(acc0[r]);
        if (two)
          C[(size_t)(r0 + 16 + q * 4 + r) * NCOLS + nt * 16 + lo] = f2bf(acc1[r]);
      }
    }
  }
}

// ---------- GAT layer 1 ----------
// One wave per dst (4 dst per 256-block).  Lane = (half h = lane>>5, w = lane&31).
// Lane covers channels w*8..w*8+7 (dwordx4 loads); half h processes edges
// beg+h, beg+h+2, ... as an independent online softmax; halves merged at end.
// Head = w>>2; per-head logit reduce = shfl_xor 1,2 (4 lanes per head).
// h1 may alias xr1 (own-row read-then-write).
__global__ __launch_bounds__(256) void k_gat1(
    const unsigned short* __restrict__ xl1, const unsigned short* __restrict__ xr1,
    const float* __restrict__ att1, const float* __restrict__ b1,
    const int* __restrict__ rowptr, const int* __restrict__ esrc,
    unsigned short* __restrict__ h1) {
  const int wave = threadIdx.x >> 6;
  const int lane = threadIdx.x & 63;
  const int dst = blockIdx.x * 4 + wave;
  if (dst >= N_NODES) return;
  const int h = lane >> 5;
  const int w = lane & 31;
  const int cb = w * 8;

  float xr[8], att[8];
  {
    ushortx8 r = *reinterpret_cast<const ushortx8*>(xr1 + (size_t)dst * C1 + cb);
    floatx4 a0 = *reinterpret_cast<const floatx4*>(att1 + cb);
    floatx4 a1 = *reinterpret_cast<const floatx4*>(att1 + cb + 4);
#pragma unroll
    for (int c = 0; c < 8; ++c) xr[c] = bf2f(r[c]);
#pragma unroll
    for (int c = 0; c < 4; ++c) { att[c] = a0[c]; att[4 + c] = a1[c]; }
  }

  const int beg = rowptr[dst], end = rowptr[dst + 1];
  const int n = end - beg;
  const int* ep = esrc + beg;

  float m = -INFINITY, l = 0.f;
  float acc[8] = {0.f, 0.f, 0.f, 0.f, 0.f, 0.f, 0.f, 0.f};

  int i = h;
  ushortx8 cur = (ushortx8)(unsigned short)0;
  if (i < n) {
    int s = ep[i];
    cur = *reinterpret_cast<const ushortx8*>(xl1 + (size_t)s * C1 + cb);
  }
  while (i < n) {
    const int inext = i + 2;
    ushortx8 nxt = cur;
    if (inext < n) {
      int s = ep[inext];
      nxt = *reinterpret_cast<const ushortx8*>(xl1 + (size_t)s * C1 + cb);
    }
    float xs[8];
#pragma unroll
    for (int c = 0; c < 8; ++c) xs[c] = bf2f(cur[c]);
    float v = 0.f;
#pragma unroll
    for (int c = 0; c < 8; ++c) {
      float e = xs[c] + xr[c];
      e = e > 0.f ? e : NEG_SLOPE * e;
      v = fmaf(e, att[c], v);
    }
    v += __shfl_xor(v, 1);
    v += __shfl_xor(v, 2);
    if (v > m) {
      const float sc = __expf(m - v);   // first edge: exp(-inf)=0
      l *= sc;
#pragma unroll
      for (int c = 0; c < 8; ++c) acc[c] *= sc;
      m = v;
    }
    const float p = __expf(v - m);
    l += p;
#pragma unroll
    for (int c = 0; c < 8; ++c) acc[c] = fmaf(p, xs[c], acc[c]);
    cur = nxt;
    i = inext;
  }

  // merge the two halves
  const float m2 = __shfl_xor(m, 32);
  const float l2 = __shfl_xor(l, 32);
  const float mm = fmaxf(m, m2);
  const float sa = (m  > -INFINITY) ? __expf(m  - mm) : 0.f;
  const float sb = (m2 > -INFINITY) ? __expf(m2 - mm) : 0.f;
  const float lt = l * sa + l2 * sb;
  float o[8];
#pragma unroll
  for (int c = 0; c < 8; ++c) {
    const float a2 = __shfl_xor(acc[c], 32);
    o[c] = acc[c] * sa + a2 * sb;
  }
  if (h == 0) {
    const float inv = 1.f / fmaxf(lt, 1e-16f);
    ushortx8 ob;
#pragma unroll
    for (int c = 0; c < 8; ++c) {
      float z = o[c] * inv + b1[cb + c];
      z = z > 0.f ? z : (__expf(z) - 1.f);   // ELU
      ob[c] = f2bf(z);
    }
    *reinterpret_cast<ushortx8*>(h1 + (size_t)dst * C1 + cb) = ob;
  }
}

// ---------- GAT layer 2 (1 head, 32 ch) fused with final linear [32x16] ----------
// One wave per dst (4 per block).  Lane = (octet o8 = lane>>3, w = lane&7).
// Lane covers channels w*4..w*4+3; octet o8 processes edges beg+o8, beg+o8+8,...
// Logit reduce = shfl_xor 1,2,4; octets merged via shfl_xor 8,16,32.
__global__ __launch_bounds__(256) void k_gat2(
    const unsigned short* __restrict__ xl2, const unsigned short* __restrict__ xr2,
    const float* __restrict__ att2, const float* __restrict__ b2,
    const float* __restrict__ Wlin, const float* __restrict__ blin,
    const int* __restrict__ rowptr, const int* __restrict__ esrc,
    float* __restrict__ out) {
  __shared__ float sh[4][32];
  const int wave = threadIdx.x >> 6;
  const int lane = threadIdx.x & 63;
  const int dst = blockIdx.x * 4 + wave;
  if (dst >= N_NODES) return;
  const int o8 = lane >> 3;
  const int w = lane & 7;
  const int cb = w * 4;

  float xr[4], att[4];
  {
    ushortx4 r = *reinterpret_cast<const ushortx4*>(xr2 + (size_t)dst * HIDC + cb);
    floatx4 a = *reinterpret_cast<const floatx4*>(att2 + cb);
#pragma unroll
    for (int c = 0; c < 4; ++c) { xr[c] = bf2f(r[c]); att[c] = a[c]; }
  }

  const int beg = rowptr[dst], end = rowptr[dst + 1];
  const int n = end - beg;
  const int* ep = esrc + beg;

  float m = -INFINITY, l = 0.f;
  float acc[4] = {0.f, 0.f, 0.f, 0.f};

  int i = o8;
  ushortx4 cur = (ushortx4)(unsigned short)0;
  if (i < n) {
    int s = ep[i];
    cur = *reinterpret_cast<const ushortx4*>(xl2 + (size_t)s * HIDC + cb);
  }
  while (i < n) {
    const int inext = i + 8;
    ushortx4 nxt = cur;
    if (inext < n) {
      int s = ep[inext];
      nxt = *reinterpret_cast<const ushortx4*>(xl2 + (size_t)s * HIDC + cb);
    }
    float xs[4];
#pragma unroll
    for (int c = 0; c < 4; ++c) xs[c] = bf2f(cur[c]);
    float v = 0.f;
#pragma unroll
    for (int c = 0; c < 4; ++c) {
      float e = xs[c] + xr[c];
      e = e > 0.f ? e : NEG_SLOPE * e;
      v = fmaf(e, att[c], v);
    }
    v += __shfl_xor(v, 1);
    v += __shfl_xor(v, 2);
    v += __shfl_xor(v, 4);
    if (v > m) {
      const float sc = __expf(m - v);
      l *= sc;
#pragma unroll
      for (int c = 0; c < 4; ++c) acc[c] *= sc;
      m = v;
    }
    const float p = __expf(v - m);
    l += p;
#pragma unroll
    for (int c = 0; c < 4; ++c) acc[c] = fmaf(p, xs[c], acc[c]);
    cur = nxt;
    i = inext;
  }

  // merge 8 octets
#pragma unroll
  for (int k = 8; k < 64; k <<= 1) {
    const float m2 = __shfl_xor(m, k);
    const float l2 = __shfl_xor(l, k);
    const float mm = fmaxf(m, m2);
    const float sa = (m  > -INFINITY) ? __expf(m  - mm) : 0.f;
    const float sb = (m2 > -INFINITY) ? __expf(m2 - mm) : 0.f;
    l = l * sa + l2 * sb;
#pragma unroll
    for (int c = 0; c < 4; ++c) {
      const float a2 = __shfl_xor(acc[c], k);
      acc[c] = acc[c] * sa + a2 * sb;
    }
    m = mm;
  }

  if (o8 == 0) {
    const float inv = 1.f / fmaxf(l, 1e-16f);
#pragma unroll
    for (int c = 0; c < 4; ++c) {
      float z = acc[c] * inv + b2[cb + c];
      z = z > 0.f ? z : (__expf(z) - 1.f);   // ELU
      sh[wave][cb + c] = z;
    }
  }
  // intra-wave LDS write->read: ordered by program order within the wave
  if (lane < OUTC) {
    float o = blin[lane];
#pragma unroll
    for (int k = 0; k < 32; ++k)
      o = fmaf(sh[wave][k], Wlin[k * OUTC + lane], o);
    out[(size_t)dst * OUTC + lane] = o;
  }
}

static inline int cdiv(int a, int b) { return (a + b - 1) / b; }

extern "C" void kernel_launch(void* const* d_in, const int* in_sizes, int n_in,
                              void* d_out, int out_size, void* d_ws, size_t ws_size,
                              hipStream_t stream) {
  const float* x    = (const float*)d_in[0];
  const int*   ei   = (const int*)d_in[1];
  const float* W1l  = (const float*)d_in[2];
  const float* W1r  = (const float*)d_in[3];
  const float* att1 = (const float*)d_in[4];
  const float* b1   = (const float*)d_in[5];
  const float* W2l  = (const float*)d_in[6];
  const float* W2r  = (const float*)d_in[7];
  const float* att2 = (const float*)d_in[8];
  const float* b2   = (const float*)d_in[9];
  const float* Wlin = (const float*)d_in[10];
  const float* blin = (const float*)d_in[11];
  float* out = (float*)d_out;

  char* w = (char*)d_ws;
  auto alloc = [&](size_t bytes) -> char* {
    char* p = w;
    w += (bytes + 255) & ~(size_t)255;
    return p;
  };
  // region A: xl1 (bf16), later reused for xl2+xr2
  char* regionA = alloc((size_t)N_NODES * C1 * 2);          // 25.6 MB
  unsigned short* xl1 = (unsigned short*)regionA;
  unsigned short* xl2 = (unsigned short*)regionA;                           // 3.2 MB
  unsigned short* xr2 = (unsigned short*)(regionA + (size_t)N_NODES * HIDC * 2 + 256);
  // region B: xr1 aliased with h1 (safe: per-wave own-row read-then-write)
  unsigned short* xr1 = (unsigned short*)alloc((size_t)N_NODES * C1 * 2);   // 25.6 MB
  unsigned short* h1  = xr1;
  unsigned short* W1lT = (unsigned short*)alloc((size_t)D_INF * C1 * 2);
  unsigned short* W1rT = (unsigned short*)alloc((size_t)D_INF * C1 * 2);
  unsigned short* W2lT = (unsigned short*)alloc((size_t)C1 * HIDC * 2);
  unsigned short* W2rT = (unsigned short*)alloc((size_t)C1 * HIDC * 2);
  int* rowptr = (int*)alloc((size_t)(N_NODES + 1) * 4);
  int* cursor = (int*)alloc((size_t)N_NODES * 4);
  int* esrc   = (int*)alloc((size_t)E_TOT * 4);
  int* flag   = (int*)alloc(4);

  hipMemsetAsync(cursor, 0, (size_t)N_NODES * 4, stream);
  k_detect<<<1, 64, 0, stream>>>(ei, flag);

  k_transpose<<<cdiv(D_INF * C1, 256), 256, 0, stream>>>(W1l, W1lT, D_INF, C1);
  k_transpose<<<cdiv(D_INF * C1, 256), 256, 0, stream>>>(W1r, W1rT, D_INF, C1);
  k_transpose<<<cdiv(C1 * HIDC, 256), 256, 0, stream>>>(W2l, W2lT, C1, HIDC);
  k_transpose<<<cdiv(C1 * HIDC, 256), 256, 0, stream>>>(W2r, W2rT, C1, HIDC);

  k_deg<<<cdiv(E_TOT, 256), 256, 0, stream>>>(ei, flag, cursor);
  k_scan<<<1, 1024, 0, stream>>>(cursor, rowptr, cursor, N_NODES);
  k_fill<<<cdiv(E_TOT, 256), 256, 0, stream>>>(ei, flag, cursor, esrc);

  const int gblocks = cdiv(cdiv(N_NODES, 32), 4);   // 391

  // GEMM1: [50000,128] x ([128,256] x2) -> xl1, xr1
  k_gemm_dual<D_INF, C1><<<gblocks, 256, 0, stream>>>(x, W1lT, W1rT, xl1, xr1, N_NODES);

  k_gat1<<<cdiv(N_NODES, 4), 256, 0, stream>>>(xl1, xr1, att1, b1, rowptr, esrc, h1);

  // GEMM2: [50000,256] x ([256,32] x2) -> xl2, xr2
  k_gemm_dual<C1, HIDC><<<gblocks, 256, 0, stream>>>(h1, W2lT, W2rT, xl2, xr2, N_NODES);

  k_gat2<<<cdiv(N_NODES, 4), 256, 0, stream>>>(xl2, xr2, att2, b2, Wlin, blin,
                                               rowptr, esrc, out);
}

// Round 4
// 276.401 us; speedup vs baseline: 2.0325x; 1.4102x over previous
//
#include <hip/hip_runtime.h>
#include <cstdint>
#include <cstddef>

#define N_NODES 50000
#define N_EDGES 400000
#define E_TOT   (N_EDGES + N_NODES)   // with self-loops
#define D_INF   128
#define C1      256                   // 8 heads * 32
#define HIDC    32
#define OUTC    16
#define NEG_SLOPE 0.2f
#define SCAN_B  ((N_NODES + 1023) / 1024)   // 49 scan blocks

typedef __bf16 bf16x8 __attribute__((ext_vector_type(8)));
typedef float  floatx4 __attribute__((ext_vector_type(4)));
typedef unsigned int uintx4 __attribute__((ext_vector_type(4)));
typedef unsigned short ushortx8 __attribute__((ext_vector_type(8)));
typedef unsigned short ushortx4 __attribute__((ext_vector_type(4)));

__device__ __forceinline__ unsigned short f2bf(float f) {
  unsigned int u = __builtin_bit_cast(unsigned int, f);
  u += 0x7FFFu + ((u >> 16) & 1u);   // RNE (finite values)
  return (unsigned short)(u >> 16);
}
__device__ __forceinline__ float bf2f(unsigned short u) {
  return __builtin_bit_cast(float, (unsigned int)u << 16);
}

// ---------- edge_index word-width autodetect ----------
__global__ void k_detect(const int* __restrict__ ei, int* __restrict__ flag) {
  __shared__ int s;
  if (threadIdx.x == 0) s = 0;
  __syncthreads();
  atomicOr(&s, ei[2 * threadIdx.x + 1]);
  __syncthreads();
  if (threadIdx.x == 0) *flag = (s == 0) ? 1 : 0;   // 1 = int64
}
__device__ __forceinline__ int ld_src(const int* ei, int f, int e) {
  return f ? ei[2 * e] : ei[e];
}
__device__ __forceinline__ int ld_dst(const int* ei, int f, int e) {
  return f ? ei[2 * (N_EDGES + e)] : ei[N_EDGES + e];
}

// ---------- transpose + f32->bf16: in[R][C] f32 -> out[C][R] bf16 ----------
__global__ void k_transpose(const float* __restrict__ in,
                            unsigned short* __restrict__ out, int R, int C) {
  int i = blockIdx.x * 256 + threadIdx.x;
  if (i < R * C) {
    int r = i / C, c = i % C;
    out[c * R + r] = f2bf(in[i]);
  }
}

// ---------- CSR build ----------
__global__ void k_deg(const int* __restrict__ ei, const int* __restrict__ flag,
                      int* __restrict__ deg) {
  int e = blockIdx.x * 256 + threadIdx.x;
  if (e < E_TOT) {
    int dst = (e < N_EDGES) ? ld_dst(ei, *flag, e) : (e - N_EDGES);
    if ((unsigned)dst < N_NODES) atomicAdd(&deg[dst], 1);
  }
}

// 3-phase device-wide exclusive scan (coalesced, all CUs)
__global__ __launch_bounds__(1024) void k_scan_blk(
    const int* __restrict__ deg, int* __restrict__ incl,
    int* __restrict__ bsum, int n) {
  __shared__ int sbuf[1024];
  const int t = threadIdx.x;
  const int i = blockIdx.x * 1024 + t;
  const int v = (i < n) ? deg[i] : 0;
  sbuf[t] = v;
  __syncthreads();
  for (int off = 1; off < 1024; off <<= 1) {
    int add = (t >= off) ? sbuf[t - off] : 0;
    __syncthreads();
    sbuf[t] += add;
    __syncthreads();
  }
  if (i < n) incl[i] = sbuf[t];
  if (t == 1023) bsum[blockIdx.x] = sbuf[1023];
}

__global__ void k_scan_top(int* __restrict__ bsum, int* __restrict__ rowptr,
                           int nb) {   // nb <= 64, one wave
  const int lane = threadIdx.x;
  const int v = (lane < nb) ? bsum[lane] : 0;
  int incl = v;
#pragma unroll
  for (int off = 1; off < 64; off <<= 1) {
    int t = __shfl_up(incl, off);
    if (lane >= off) incl += t;
  }
  if (lane < nb) bsum[lane] = incl - v;   // exclusive block offset
  if (lane == 63) rowptr[N_NODES] = incl; // grand total
}

__global__ __launch_bounds__(1024) void k_scan_add(
    const int* __restrict__ deg, const int* __restrict__ incl,
    const int* __restrict__ bsum, int* __restrict__ rowptr,
    int* __restrict__ cursor, int n) {
  const int i = blockIdx.x * 1024 + threadIdx.x;
  if (i < n) {
    const int e = bsum[blockIdx.x] + incl[i] - deg[i];
    rowptr[i] = e;
    cursor[i] = e;
  }
}

__global__ void k_fill(const int* __restrict__ ei, const int* __restrict__ flag,
                       int* __restrict__ cursor, int* __restrict__ esrc) {
  int e = blockIdx.x * 256 + threadIdx.x;
  if (e < E_TOT) {
    int src, dst;
    if (e < N_EDGES) { src = ld_src(ei, *flag, e); dst = ld_dst(ei, *flag, e); }
    else             { src = dst = e - N_EDGES; }
    if ((unsigned)src < N_NODES && (unsigned)dst < N_NODES) {
      int pos = atomicAdd(&cursor[dst], 1);
      esrc[pos] = src;
    }
  }
}

// ---------- A-fragment loaders (8 contiguous k-elements -> bf16x8) ----------
__device__ __forceinline__ bf16x8 load8(const unsigned short* p) {
  uintx4 raw = *reinterpret_cast<const uintx4*>(p);
  return __builtin_bit_cast(bf16x8, raw);
}
__device__ __forceinline__ bf16x8 load8(const float* p) {
  floatx4 a = *reinterpret_cast<const floatx4*>(p);
  floatx4 b = *reinterpret_cast<const floatx4*>(p + 4);
  ushortx8 u;
#pragma unroll
  for (int i = 0; i < 4; ++i) { u[i] = f2bf(a[i]); u[4 + i] = f2bf(b[i]); }
  return __builtin_bit_cast(bf16x8, u);
}

// ---------- dual MFMA bf16 GEMM: C{0,1}[M][NCOLS] = A[M][K] * BT{0,1}^T ----------
template <int K, int NCOLS, typename AT>
__global__ __launch_bounds__(256) void k_gemm_dual(
    const AT* __restrict__ A,
    const unsigned short* __restrict__ BT0, const unsigned short* __restrict__ BT1,
    unsigned short* __restrict__ C0, unsigned short* __restrict__ C1_, int M) {
  const int wave = threadIdx.x >> 6;
  const int lane = threadIdx.x & 63;
  const int lo = lane & 15;   // m for A, n for B, col for C/D
  const int q  = lane >> 4;   // k-chunk quad
  const int unit = blockIdx.x * 4 + wave;
  const int r0 = unit * 32;
  if (r0 >= M) return;
  const bool two = (r0 + 16) < M;
  constexpr int KB = K / 32;

  bf16x8 afrag[2][KB];
#pragma unroll
  for (int kb = 0; kb < KB; ++kb)
    afrag[0][kb] = load8(A + (size_t)(r0 + lo) * K + kb * 32 + q * 8);
  if (two) {
#pragma unroll
    for (int kb = 0; kb < KB; ++kb)
      afrag[1][kb] = load8(A + (size_t)(r0 + 16 + lo) * K + kb * 32 + q * 8);
  }

#pragma unroll
  for (int o = 0; o < 2; ++o) {
    const unsigned short* BT = o ? BT1 : BT0;
    unsigned short* C = o ? C1_ : C0;
#pragma unroll
    for (int nt = 0; nt < NCOLS / 16; ++nt) {
      floatx4 acc0 = {0.f, 0.f, 0.f, 0.f};
      floatx4 acc1 = {0.f, 0.f, 0.f, 0.f};
      const unsigned short* bptr = BT + (size_t)(nt * 16 + lo) * K + q * 8;
#pragma unroll
      for (int kb = 0; kb < KB; ++kb) {
        bf16x8 b = load8(bptr + kb * 32);
        acc0 = __builtin_amdgcn_mfma_f32_16x16x32_bf16(afrag[0][kb], b, acc0, 0, 0, 0);
        if (two)
          acc1 = __builtin_amdgcn_mfma_f32_16x16x32_bf16(afrag[1][kb], b, acc1, 0, 0, 0);
      }
      // C/D layout: col = lane&15, row = (lane>>4)*4 + reg   [m89-verified]
#pragma unroll
      for (int r = 0; r < 4; ++r) {
        C[(size_t)(r0 + q * 4 + r) * NCOLS + nt * 16 + lo] = f2bf(acc0[r]);
        if (two)
          C[(size_t)(r0 + 16 + q * 4 + r) * NCOLS + nt * 16 + lo] = f2bf(acc1[r]);
      }
    }
  }
}

// ---------- GAT layer 1 ----------
// One wave per dst (4 per block); lane = (half h = lane>>5, w = lane&31),
// channels w*8..w*8+7; halves process alternating edges; merged at end.
// h1 may alias xr1 (own-row read-then-write).
__global__ __launch_bounds__(256) void k_gat1(
    const unsigned short* __restrict__ xl1, const unsigned short* __restrict__ xr1,
    const float* __restrict__ att1, const float* __restrict__ b1,
    const int* __restrict__ rowptr, const int* __restrict__ esrc,
    unsigned short* __restrict__ h1) {
  const int wave = threadIdx.x >> 6;
  const int lane = threadIdx.x & 63;
  const int dst = blockIdx.x * 4 + wave;
  if (dst >= N_NODES) return;
  const int h = lane >> 5;
  const int w = lane & 31;
  const int cb = w * 8;

  float xr[8], att[8];
  {
    ushortx8 r = *reinterpret_cast<const ushortx8*>(xr1 + (size_t)dst * C1 + cb);
    floatx4 a0 = *reinterpret_cast<const floatx4*>(att1 + cb);
    floatx4 a1 = *reinterpret_cast<const floatx4*>(att1 + cb + 4);
#pragma unroll
    for (int c = 0; c < 8; ++c) xr[c] = bf2f(r[c]);
#pragma unroll
    for (int c = 0; c < 4; ++c) { att[c] = a0[c]; att[4 + c] = a1[c]; }
  }

  const int beg = rowptr[dst], end = rowptr[dst + 1];
  const int n = end - beg;
  const int* ep = esrc + beg;

  float m = -INFINITY, l = 0.f;
  float acc[8] = {0.f, 0.f, 0.f, 0.f, 0.f, 0.f, 0.f, 0.f};

  int i = h;
  ushortx8 cur = (ushortx8)(unsigned short)0;
  if (i < n) {
    int s = ep[i];
    cur = *reinterpret_cast<const ushortx8*>(xl1 + (size_t)s * C1 + cb);
  }
  while (i < n) {
    const int inext = i + 2;
    ushortx8 nxt = cur;
    if (inext < n) {
      int s = ep[inext];
      nxt = *reinterpret_cast<const ushortx8*>(xl1 + (size_t)s * C1 + cb);
    }
    float xs[8];
#pragma unroll
    for (int c = 0; c < 8; ++c) xs[c] = bf2f(cur[c]);
    float v = 0.f;
#pragma unroll
    for (int c = 0; c < 8; ++c) {
      float e = xs[c] + xr[c];
      e = e > 0.f ? e : NEG_SLOPE * e;
      v = fmaf(e, att[c], v);
    }
    v += __shfl_xor(v, 1);
    v += __shfl_xor(v, 2);
    if (v > m) {
      const float sc = __expf(m - v);   // first edge: exp(-inf)=0
      l *= sc;
#pragma unroll
      for (int c = 0; c < 8; ++c) acc[c] *= sc;
      m = v;
    }
    const float p = __expf(v - m);
    l += p;
#pragma unroll
    for (int c = 0; c < 8; ++c) acc[c] = fmaf(p, xs[c], acc[c]);
    cur = nxt;
    i = inext;
  }

  // merge the two halves
  const float m2 = __shfl_xor(m, 32);
  const float l2 = __shfl_xor(l, 32);
  const float mm = fmaxf(m, m2);
  const float sa = (m  > -INFINITY) ? __expf(m  - mm) : 0.f;
  const float sb = (m2 > -INFINITY) ? __expf(m2 - mm) : 0.f;
  const float lt = l * sa + l2 * sb;
  float o[8];
#pragma unroll
  for (int c = 0; c < 8; ++c) {
    const float a2 = __shfl_xor(acc[c], 32);
    o[c] = acc[c] * sa + a2 * sb;
  }
  if (h == 0) {
    const float inv = 1.f / fmaxf(lt, 1e-16f);
    ushortx8 ob;
#pragma unroll
    for (int c = 0; c < 8; ++c) {
      float z = o[c] * inv + b1[cb + c];
      z = z > 0.f ? z : (__expf(z) - 1.f);   // ELU
      ob[c] = f2bf(z);
    }
    *reinterpret_cast<ushortx8*>(h1 + (size_t)dst * C1 + cb) = ob;
  }
}

// ---------- GAT layer 2 (1 head, 32 ch) fused with final linear [32x16] ----------
__global__ __launch_bounds__(256) void k_gat2(
    const unsigned short* __restrict__ xl2, const unsigned short* __restrict__ xr2,
    const float* __restrict__ att2, const float* __restrict__ b2,
    const float* __restrict__ Wlin, const float* __restrict__ blin,
    const int* __restrict__ rowptr, const int* __restrict__ esrc,
    float* __restrict__ out) {
  __shared__ float sh[4][32];
  const int wave = threadIdx.x >> 6;
  const int lane = threadIdx.x & 63;
  const int dst = blockIdx.x * 4 + wave;
  if (dst >= N_NODES) return;
  const int o8 = lane >> 3;
  const int w = lane & 7;
  const int cb = w * 4;

  float xr[4], att[4];
  {
    ushortx4 r = *reinterpret_cast<const ushortx4*>(xr2 + (size_t)dst * HIDC + cb);
    floatx4 a = *reinterpret_cast<const floatx4*>(att2 + cb);
#pragma unroll
    for (int c = 0; c < 4; ++c) { xr[c] = bf2f(r[c]); att[c] = a[c]; }
  }

  const int beg = rowptr[dst], end = rowptr[dst + 1];
  const int n = end - beg;
  const int* ep = esrc + beg;

  float m = -INFINITY, l = 0.f;
  float acc[4] = {0.f, 0.f, 0.f, 0.f};

  int i = o8;
  ushortx4 cur = (ushortx4)(unsigned short)0;
  if (i < n) {
    int s = ep[i];
    cur = *reinterpret_cast<const ushortx4*>(xl2 + (size_t)s * HIDC + cb);
  }
  while (i < n) {
    const int inext = i + 8;
    ushortx4 nxt = cur;
    if (inext < n) {
      int s = ep[inext];
      nxt = *reinterpret_cast<const ushortx4*>(xl2 + (size_t)s * HIDC + cb);
    }
    float xs[4];
#pragma unroll
    for (int c = 0; c < 4; ++c) xs[c] = bf2f(cur[c]);
    float v = 0.f;
#pragma unroll
    for (int c = 0; c < 4; ++c) {
      float e = xs[c] + xr[c];
      e = e > 0.f ? e : NEG_SLOPE * e;
      v = fmaf(e, att[c], v);
    }
    v += __shfl_xor(v, 1);
    v += __shfl_xor(v, 2);
    v += __shfl_xor(v, 4);
    if (v > m) {
      const float sc = __expf(m - v);
      l *= sc;
#pragma unroll
      for (int c = 0; c < 4; ++c) acc[c] *= sc;
      m = v;
    }
    const float p = __expf(v - m);
    l += p;
#pragma unroll
    for (int c = 0; c < 4; ++c) acc[c] = fmaf(p, xs[c], acc[c]);
    cur = nxt;
    i = inext;
  }

  // merge 8 octets
#pragma unroll
  for (int k = 8; k < 64; k <<= 1) {
    const float m2 = __shfl_xor(m, k);
    const float l2 = __shfl_xor(l, k);
    const float mm = fmaxf(m, m2);
    const float sa = (m  > -INFINITY) ? __expf(m  - mm) : 0.f;
    const float sb = (m2 > -INFINITY) ? __expf(m2 - mm) : 0.f;
    l = l * sa + l2 * sb;
#pragma unroll
    for (int c = 0; c < 4; ++c) {
      const float a2 = __shfl_xor(acc[c], k);
      acc[c] = acc[c] * sa + a2 * sb;
    }
    m = mm;
  }

  if (o8 == 0) {
    const float inv = 1.f / fmaxf(l, 1e-16f);
#pragma unroll
    for (int c = 0; c < 4; ++c) {
      float z = acc[c] * inv + b2[cb + c];
      z = z > 0.f ? z : (__expf(z) - 1.f);   // ELU
      sh[wave][cb + c] = z;
    }
  }
  if (lane < OUTC) {
    float o = blin[lane];
#pragma unroll
    for (int k = 0; k < 32; ++k)
      o = fmaf(sh[wave][k], Wlin[k * OUTC + lane], o);
    out[(size_t)dst * OUTC + lane] = o;
  }
}

static inline int cdiv(int a, int b) { return (a + b - 1) / b; }

extern "C" void kernel_launch(void* const* d_in, const int* in_sizes, int n_in,
                              void* d_out, int out_size, void* d_ws, size_t ws_size,
                              hipStream_t stream) {
  const float* x    = (const float*)d_in[0];
  const int*   ei   = (const int*)d_in[1];
  const float* W1l  = (const float*)d_in[2];
  const float* W1r  = (const float*)d_in[3];
  const float* att1 = (const float*)d_in[4];
  const float* b1   = (const float*)d_in[5];
  const float* W2l  = (const float*)d_in[6];
  const float* W2r  = (const float*)d_in[7];
  const float* att2 = (const float*)d_in[8];
  const float* b2   = (const float*)d_in[9];
  const float* Wlin = (const float*)d_in[10];
  const float* blin = (const float*)d_in[11];
  float* out = (float*)d_out;

  char* w = (char*)d_ws;
  auto alloc = [&](size_t bytes) -> char* {
    char* p = w;
    w += (bytes + 255) & ~(size_t)255;
    return p;
  };
  // region A: xl1 (bf16), later reused for xl2+xr2
  char* regionA = alloc((size_t)N_NODES * C1 * 2);          // 25.6 MB
  unsigned short* xl1 = (unsigned short*)regionA;
  unsigned short* xl2 = (unsigned short*)regionA;                           // 3.2 MB
  unsigned short* xr2 = (unsigned short*)(regionA + (size_t)N_NODES * HIDC * 2 + 256);
  // region B: xr1 aliased with h1 (safe: per-wave own-row read-then-write)
  unsigned short* xr1 = (unsigned short*)alloc((size_t)N_NODES * C1 * 2);   // 25.6 MB
  unsigned short* h1  = xr1;
  unsigned short* W1lT = (unsigned short*)alloc((size_t)D_INF * C1 * 2);
  unsigned short* W1rT = (unsigned short*)alloc((size_t)D_INF * C1 * 2);
  unsigned short* W2lT = (unsigned short*)alloc((size_t)C1 * HIDC * 2);
  unsigned short* W2rT = (unsigned short*)alloc((size_t)C1 * HIDC * 2);
  int* rowptr = (int*)alloc((size_t)(N_NODES + 1) * 4);
  int* cursor = (int*)alloc((size_t)N_NODES * 4);
  int* deg    = (int*)alloc((size_t)N_NODES * 4);
  int* incl   = (int*)alloc((size_t)N_NODES * 4);
  int* bsum   = (int*)alloc((size_t)SCAN_B * 4);
  int* esrc   = (int*)alloc((size_t)E_TOT * 4);
  int* flag   = (int*)alloc(4);

  hipMemsetAsync(deg, 0, (size_t)N_NODES * 4, stream);
  k_detect<<<1, 64, 0, stream>>>(ei, flag);

  k_transpose<<<cdiv(D_INF * C1, 256), 256, 0, stream>>>(W1l, W1lT, D_INF, C1);
  k_transpose<<<cdiv(D_INF * C1, 256), 256, 0, stream>>>(W1r, W1rT, D_INF, C1);
  k_transpose<<<cdiv(C1 * HIDC, 256), 256, 0, stream>>>(W2l, W2lT, C1, HIDC);
  k_transpose<<<cdiv(C1 * HIDC, 256), 256, 0, stream>>>(W2r, W2rT, C1, HIDC);

  k_deg<<<cdiv(E_TOT, 256), 256, 0, stream>>>(ei, flag, deg);
  k_scan_blk<<<SCAN_B, 1024, 0, stream>>>(deg, incl, bsum, N_NODES);
  k_scan_top<<<1, 64, 0, stream>>>(bsum, rowptr, SCAN_B);
  k_scan_add<<<SCAN_B, 1024, 0, stream>>>(deg, incl, bsum, rowptr, cursor, N_NODES);
  k_fill<<<cdiv(E_TOT, 256), 256, 0, stream>>>(ei, flag, cursor, esrc);

  const int gblocks = cdiv(cdiv(N_NODES, 32), 4);   // 391

  // GEMM1: [50000,128] x ([128,256] x2) -> xl1, xr1
  k_gemm_dual<D_INF, C1><<<gblocks, 256, 0, stream>>>(x, W1lT, W1rT, xl1, xr1, N_NODES);

  k_gat1<<<cdiv(N_NODES, 4), 256, 0, stream>>>(xl1, xr1, att1, b1, rowptr, esrc, h1);

  // GEMM2: [50000,256] x ([256,32] x2) -> xl2, xr2
  k_gemm_dual<C1, HIDC><<<gblocks, 256, 0, stream>>>(h1, W2lT, W2rT, xl2, xr2, N_NODES);

  k_gat2<<<cdiv(N_NODES, 4), 256, 0, stream>>>(xl2, xr2, att2, b2, Wlin, blin,
                                               rowptr, esrc, out);
}